// Round 5
// baseline (504.167 us; speedup 1.0000x reference)
//
#include <hip/hip_runtime.h>
#include <hip/hip_bf16.h>

#define NHEAD 4

typedef __hip_bfloat16 bf16;
typedef __hip_bfloat162 bf162;
typedef float f32x4 __attribute__((ext_vector_type(4)));  // NT-store-able 16B

// ---------------------------------------------------------------------------
// Kernel 1: fused QKV projection + denom zeroing.
// 256 threads; block = 16 nodes; wave qg owns nodes qg*4..qg*4+3.
// q,k stored bf16 HEAD-MAJOR: q[h][node][d] so each per-head pass of the
// edge kernel has a 3.2MB working set (fits per-XCD 4MB L2).
// v fp32 direct to out in [N, d, h]. denom[4*N] zeroed by first 200K threads.
// ---------------------------------------------------------------------------
__global__ __launch_bounds__(256) void qkv_kernel(
    const float* __restrict__ x,
    const float* __restrict__ Wq, const float* __restrict__ bq,
    const float* __restrict__ Wk, const float* __restrict__ bk,
    const float* __restrict__ Wv, const float* __restrict__ bv,
    bf16* __restrict__ qout, bf16* __restrict__ kout,
    float* __restrict__ vout, float* __restrict__ denom, int n_nodes) {
  const long long gtid = (long long)blockIdx.x * 256 + threadIdx.x;
  if (gtid < (long long)n_nodes * NHEAD) denom[gtid] = 0.f;

  __shared__ float xs[16][64];
  const int t = threadIdx.x;
  const int base = blockIdx.x * 16;
#pragma unroll
  for (int j = 0; j < 4; ++j) {
    const int idx = t + 256 * j;
    const int nn = idx >> 6, cc = idx & 63;
    xs[nn][cc] = (base + nn < n_nodes)
                     ? __builtin_nontemporal_load(&x[(size_t)(base + nn) * 64 + cc])
                     : 0.f;
  }
  __syncthreads();
  const int c = t & 63;
  const int qg = t >> 6;  // wave id

  float aq[4], ak[4], av[4];
  const float bqv = bq[c], bkv = bk[c], bvv = bv[c];
#pragma unroll
  for (int j = 0; j < 4; ++j) { aq[j] = bqv; ak[j] = bkv; av[j] = bvv; }

#pragma unroll 4
  for (int r = 0; r < 64; ++r) {
    const float wq = Wq[r * 64 + c];
    const float wk = Wk[r * 64 + c];
    const float wv = Wv[r * 64 + c];
#pragma unroll
    for (int j = 0; j < 4; ++j) {
      const float xv = xs[qg * 4 + j][r];  // wave-uniform addr -> LDS broadcast
      aq[j] = fmaf(xv, wq, aq[j]);
      ak[j] = fmaf(xv, wk, ak[j]);
      av[j] = fmaf(xv, wv, av[j]);
    }
  }
  const int h = c >> 4, d = c & 15;
#pragma unroll
  for (int j = 0; j < 4; ++j) {
    const int node = base + qg * 4 + j;
    if (node < n_nodes) {
      qout[((size_t)h * n_nodes + node) * 16 + d] = __float2bfloat16(aq[j]);
      kout[((size_t)h * n_nodes + node) * 16 + d] = __float2bfloat16(ak[j]);
      __builtin_nontemporal_store(av[j], &vout[(size_t)node * 64 + d * 4 + h]);
    }
  }
}

// ---------------------------------------------------------------------------
// Kernel 2: per-(head, edge) dot + denominator atomics, head-phased.
// Grid = 4 * bph blocks; head = blockIdx.x / bph. Blocks of one head
// dispatch (approximately) together -> q_h,k_h (3.2MB) resident in each
// XCD's L2; denom_h (200KB) resident -> no dirty-line thrash.
// prods written TRANSPOSED [4][E] (contiguous per pass), NT.
// ---------------------------------------------------------------------------
__device__ __forceinline__ float dot8(uint4 a, uint4 b) {
  const unsigned* pa = &a.x;
  const unsigned* pb = &b.x;
  float acc = 0.f;
#pragma unroll
  for (int i = 0; i < 4; ++i) {
    const float2 fa = __bfloat1622float2(*(const bf162*)&pa[i]);
    const float2 fb = __bfloat1622float2(*(const bf162*)&pb[i]);
    acc = fmaf(fa.x, fb.x, acc);
    acc = fmaf(fa.y, fb.y, acc);
  }
  return acc;
}

__global__ __launch_bounds__(256) void edge_kernel(
    const int* __restrict__ edge0, const int* __restrict__ edge1,
    const uint4* __restrict__ q, const uint4* __restrict__ k,
    float* __restrict__ prods_t, float* __restrict__ denom,
    int n_edges, int n_nodes, int bph) {
  const int h = blockIdx.x / bph;
  const int e = (blockIdx.x - h * bph) * 256 + threadIdx.x;
  if (e >= n_edges) return;
  const int src = __builtin_nontemporal_load(&edge0[e]);
  const int dst = __builtin_nontemporal_load(&edge1[e]);

  // per-head row = 32B = 2 uint4
  const size_t qb = ((size_t)h * n_nodes + src) * 2;
  const size_t kb = ((size_t)h * n_nodes + dst) * 2;
  const uint4 a0 = q[qb], a1 = q[qb + 1];
  const uint4 b0 = k[kb], b1 = k[kb + 1];

  const float p = (dot8(a0, b0) + dot8(a1, b1)) * 0.25f;  // 1/sqrt(16)
  __builtin_nontemporal_store(p, &prods_t[(size_t)h * n_edges + e]);
  atomicAdd(&denom[h * n_nodes + src], __expf(p));
}

// ---------------------------------------------------------------------------
// Kernel 3: one thread per edge. Reads prods_t[4][E] (4 coalesced streams),
// writes attn[e][0..3] and prods[e][0..3] as single 16B NT stores.
// ---------------------------------------------------------------------------
__global__ __launch_bounds__(256) void norm_kernel(
    const int* __restrict__ edge0, const float* __restrict__ denom,
    const float* __restrict__ prods_t, f32x4* __restrict__ attn4,
    f32x4* __restrict__ prods4, int n_edges, int n_nodes) {
  const int e = blockIdx.x * 256 + threadIdx.x;
  if (e >= n_edges) return;
  const int seg = __builtin_nontemporal_load(&edge0[e]);
  float p[4], a[4];
#pragma unroll
  for (int h = 0; h < 4; ++h) {
    p[h] = __builtin_nontemporal_load(&prods_t[(size_t)h * n_edges + e]);
    a[h] = __expf(p[h]) / (denom[h * n_nodes + seg] + 1e-16f);
  }
  const f32x4 av = {a[0], a[1], a[2], a[3]};
  const f32x4 pv = {p[0], p[1], p[2], p[3]};
  __builtin_nontemporal_store(av, &attn4[e]);
  __builtin_nontemporal_store(pv, &prods4[e]);
}

extern "C" void kernel_launch(void* const* d_in, const int* in_sizes, int n_in,
                              void* d_out, int out_size, void* d_ws, size_t ws_size,
                              hipStream_t stream) {
  const float* x  = (const float*)d_in[0];
  const int* edge = (const int*)d_in[1];
  const float* Wq = (const float*)d_in[2];
  const float* bq = (const float*)d_in[3];
  const float* Wk = (const float*)d_in[4];
  const float* bk = (const float*)d_in[5];
  const float* Wv = (const float*)d_in[6];
  const float* bv = (const float*)d_in[7];

  const int n_nodes = in_sizes[0] / 64;   // 50000
  const int n_edges = in_sizes[1] / 2;    // 1600000
  const int* edge0 = edge;
  const int* edge1 = edge + n_edges;

  // Output: attention [E*4] | v [N*64] | prods [E*4]
  float* out_attn  = (float*)d_out;
  float* out_v     = out_attn + (long long)n_edges * NHEAD;
  float* out_prods = out_v + (long long)n_nodes * 64;

  // Workspace: q bf16 [4][N][16] | k bf16 [4][N][16] | prods_t f32 [4][E]
  //            | denom f32 [4][N]   (total ~39.2MB)
  bf16* ws_q = (bf16*)d_ws;
  bf16* ws_k = ws_q + (size_t)NHEAD * n_nodes * 16;
  float* ws_prods = (float*)(ws_k + (size_t)NHEAD * n_nodes * 16);
  float* ws_denom = ws_prods + (size_t)NHEAD * n_edges;

  {
    const int blocks = (n_nodes + 15) / 16;
    qkv_kernel<<<blocks, 256, 0, stream>>>(x, Wq, bq, Wk, bk, Wv, bv,
                                           ws_q, ws_k, out_v, ws_denom, n_nodes);
  }
  {
    const int bph = (n_edges + 255) / 256;  // blocks per head phase
    edge_kernel<<<bph * NHEAD, 256, 0, stream>>>(
        edge0, edge1, (const uint4*)ws_q, (const uint4*)ws_k,
        ws_prods, ws_denom, n_edges, n_nodes, bph);
  }
  {
    const int blocks = (n_edges + 255) / 256;
    norm_kernel<<<blocks, 256, 0, stream>>>(edge0, ws_denom, ws_prods,
                                            (f32x4*)out_attn, (f32x4*)out_prods,
                                            n_edges, n_nodes);
  }
}

// Round 6
// 217.501 us; speedup vs baseline: 2.3180x; 2.3180x over previous
//
#include <hip/hip_runtime.h>
#include <hip/hip_bf16.h>

#define NHEAD 4

typedef __hip_bfloat16 bf16;
typedef __hip_bfloat162 bf162;
typedef float f32x4 __attribute__((ext_vector_type(4)));  // native vec, NT-able

// ---------------------------------------------------------------------------
// Kernel 1: fused QKV projection + denom zeroing (no separate memset).
// 256 threads; block = 16 nodes; wave qg owns nodes qg*4..qg*4+3; each W
// element feeds 4 FMAs. q,k bf16 [node][64] (col = h*16+d) -> per-edge 128B
// contiguous gather rows. v fp32 direct to out in [N, d, h] layout.
// ---------------------------------------------------------------------------
__global__ __launch_bounds__(256) void qkv_kernel(
    const float* __restrict__ x,
    const float* __restrict__ Wq, const float* __restrict__ bq,
    const float* __restrict__ Wk, const float* __restrict__ bk,
    const float* __restrict__ Wv, const float* __restrict__ bv,
    bf16* __restrict__ qout, bf16* __restrict__ kout,
    float* __restrict__ vout, float* __restrict__ denom, int n_nodes) {
  const long long gtid = (long long)blockIdx.x * 256 + threadIdx.x;
  if (gtid < (long long)n_nodes * NHEAD) denom[gtid] = 0.f;

  __shared__ float xs[16][64];
  const int t = threadIdx.x;
  const int base = blockIdx.x * 16;
#pragma unroll
  for (int j = 0; j < 4; ++j) {
    const int idx = t + 256 * j;
    const int nn = idx >> 6, cc = idx & 63;
    xs[nn][cc] = (base + nn < n_nodes)
                     ? __builtin_nontemporal_load(&x[(size_t)(base + nn) * 64 + cc])
                     : 0.f;
  }
  __syncthreads();
  const int c = t & 63;
  const int qg = t >> 6;  // wave id

  float aq[4], ak[4], av[4];
  const float bqv = bq[c], bkv = bk[c], bvv = bv[c];
#pragma unroll
  for (int j = 0; j < 4; ++j) { aq[j] = bqv; ak[j] = bkv; av[j] = bvv; }

#pragma unroll 4
  for (int r = 0; r < 64; ++r) {
    const float wq = Wq[r * 64 + c];
    const float wk = Wk[r * 64 + c];
    const float wv = Wv[r * 64 + c];
#pragma unroll
    for (int j = 0; j < 4; ++j) {
      const float xv = xs[qg * 4 + j][r];  // wave-uniform addr -> LDS broadcast
      aq[j] = fmaf(xv, wq, aq[j]);
      ak[j] = fmaf(xv, wk, ak[j]);
      av[j] = fmaf(xv, wv, av[j]);
    }
  }
#pragma unroll
  for (int j = 0; j < 4; ++j) {
    const int node = base + qg * 4 + j;
    if (node < n_nodes) {
      qout[(size_t)node * 64 + c] = __float2bfloat16(aq[j]);
      kout[(size_t)node * 64 + c] = __float2bfloat16(ak[j]);
      vout[(size_t)node * 64 + (c & 15) * 4 + (c >> 4)] = av[j];  // regular store
    }
  }
}

// ---------------------------------------------------------------------------
// Kernel 2: per-(edge,head) dot + denom atomics, TWO edges per thread
// (e and e+half) for 2x memory-level parallelism (8 outstanding gather
// loads/thread; R3 had 4 and was latency-bound at VALUBusy=13%).
// 4 lanes (heads) of one edge read one contiguous 128B q/k row; their
// denom atomics hit one 16B cluster -> same-line coalescing (R3 layout).
// prods written straight to the final [E][4] output slot, regular stores.
// ---------------------------------------------------------------------------
__device__ __forceinline__ float dot8(uint4 a, uint4 b) {
  const unsigned* pa = &a.x;
  const unsigned* pb = &b.x;
  float acc = 0.f;
#pragma unroll
  for (int i = 0; i < 4; ++i) {
    const float2 fa = __bfloat1622float2(*(const bf162*)&pa[i]);
    const float2 fb = __bfloat1622float2(*(const bf162*)&pb[i]);
    acc = fmaf(fa.x, fb.x, acc);
    acc = fmaf(fa.y, fb.y, acc);
  }
  return acc;
}

__global__ __launch_bounds__(256) void edge_kernel(
    const int* __restrict__ edge0, const int* __restrict__ edge1,
    const uint4* __restrict__ q, const uint4* __restrict__ k,
    float* __restrict__ prods, float* __restrict__ denom, int n_edges) {
  const int i = blockIdx.x * 256 + threadIdx.x;
  const int half = (n_edges + 1) >> 1;
  const int e0 = i >> 2;
  const int h = i & 3;
  if (e0 >= half) return;
  const int e1 = e0 + half;
  const bool two = (e1 < n_edges);
  const int eb = two ? e1 : e0;

  const int src0 = __builtin_nontemporal_load(&edge0[e0]);
  const int dst0 = __builtin_nontemporal_load(&edge1[e0]);
  const int src1 = __builtin_nontemporal_load(&edge0[eb]);
  const int dst1 = __builtin_nontemporal_load(&edge1[eb]);

  // bf16 row = 128B = 8 uint4; head h = slots 2h, 2h+1
  const size_t qb0 = (size_t)src0 * 8 + h * 2;
  const size_t kb0 = (size_t)dst0 * 8 + h * 2;
  const size_t qb1 = (size_t)src1 * 8 + h * 2;
  const size_t kb1 = (size_t)dst1 * 8 + h * 2;
  const uint4 a00 = q[qb0], a01 = q[qb0 + 1];
  const uint4 b00 = k[kb0], b01 = k[kb0 + 1];
  const uint4 a10 = q[qb1], a11 = q[qb1 + 1];
  const uint4 b10 = k[kb1], b11 = k[kb1 + 1];

  const float p0 = (dot8(a00, b00) + dot8(a01, b01)) * 0.25f;  // 1/sqrt(16)
  prods[(size_t)e0 * 4 + h] = p0;
  atomicAdd(&denom[src0 * 4 + h], __expf(p0));
  if (two) {
    const float p1 = (dot8(a10, b10) + dot8(a11, b11)) * 0.25f;
    prods[(size_t)e1 * 4 + h] = p1;
    atomicAdd(&denom[src1 * 4 + h], __expf(p1));
  }
}

// ---------------------------------------------------------------------------
// Kernel 3: one thread per edge. f32x4 load of prods[e][0..3] (already in
// final output position) + f32x4 load of denom[seg][0..3]; one 16B NT store
// of attn (full-line coverage per wave -> safe for NT).
// ---------------------------------------------------------------------------
__global__ __launch_bounds__(256) void norm_kernel(
    const int* __restrict__ edge0, const float* __restrict__ denom,
    const f32x4* __restrict__ prods4, f32x4* __restrict__ attn4, int n_edges) {
  const int e = blockIdx.x * 256 + threadIdx.x;
  if (e >= n_edges) return;
  const int seg = __builtin_nontemporal_load(&edge0[e]);
  const f32x4 p = prods4[e];
  const f32x4 den = *(const f32x4*)&denom[(size_t)seg * 4];
  f32x4 a;
  a.x = __expf(p.x) / (den.x + 1e-16f);
  a.y = __expf(p.y) / (den.y + 1e-16f);
  a.z = __expf(p.z) / (den.z + 1e-16f);
  a.w = __expf(p.w) / (den.w + 1e-16f);
  __builtin_nontemporal_store(a, &attn4[e]);
}

extern "C" void kernel_launch(void* const* d_in, const int* in_sizes, int n_in,
                              void* d_out, int out_size, void* d_ws, size_t ws_size,
                              hipStream_t stream) {
  const float* x  = (const float*)d_in[0];
  const int* edge = (const int*)d_in[1];
  const float* Wq = (const float*)d_in[2];
  const float* bq = (const float*)d_in[3];
  const float* Wk = (const float*)d_in[4];
  const float* bk = (const float*)d_in[5];
  const float* Wv = (const float*)d_in[6];
  const float* bv = (const float*)d_in[7];

  const int n_nodes = in_sizes[0] / 64;   // 50000
  const int n_edges = in_sizes[1] / 2;    // 1600000
  const int* edge0 = edge;
  const int* edge1 = edge + n_edges;

  // Output: attention [E*4] | v [N*64] | prods [E*4]
  float* out_attn  = (float*)d_out;
  float* out_v     = out_attn + (long long)n_edges * NHEAD;
  float* out_prods = out_v + (long long)n_nodes * 64;

  // Workspace: q bf16 [N][64] | k bf16 [N][64] | denom f32 [N][4]  (~13.6MB)
  bf16* ws_q = (bf16*)d_ws;
  bf16* ws_k = ws_q + (size_t)n_nodes * 64;
  float* ws_denom = (float*)(ws_k + (size_t)n_nodes * 64);

  {
    const int blocks = (n_nodes + 15) / 16;  // 3125 blocks; covers denom zeroing
    qkv_kernel<<<blocks, 256, 0, stream>>>(x, Wq, bq, Wk, bk, Wv, bv,
                                           ws_q, ws_k, out_v, ws_denom, n_nodes);
  }
  {
    const int half = (n_edges + 1) >> 1;
    const long long total = (long long)half * NHEAD;
    const int blocks = (int)((total + 255) / 256);
    edge_kernel<<<blocks, 256, 0, stream>>>(edge0, edge1,
                                            (const uint4*)ws_q, (const uint4*)ws_k,
                                            out_prods, ws_denom, n_edges);
  }
  {
    const int blocks = (n_edges + 255) / 256;
    norm_kernel<<<blocks, 256, 0, stream>>>(edge0, ws_denom,
                                            (const f32x4*)out_prods,
                                            (f32x4*)out_attn, n_edges);
  }
}